// Round 18
// baseline (351.705 us; speedup 1.0000x reference)
//
#include <hip/hip_runtime.h>
#include <hip/hip_fp16.h>

#define BB 2
#define HH 512
#define WW 512
#define CC 64
#define PW 514

typedef _Float16 f16;
typedef _Float16 f16x8 __attribute__((ext_vector_type(8)));
typedef float f32x4 __attribute__((ext_vector_type(4)));

static __device__ __forceinline__ f16x8 zero_f16x8() {
    f16x8 z = {(f16)0,(f16)0,(f16)0,(f16)0,(f16)0,(f16)0,(f16)0,(f16)0};
    return z;
}

static __device__ __forceinline__ f16x8 cvt_pair(f32x4 a, f32x4 b) {
    f16x8 o;
    o[0]=(f16)a[0]; o[1]=(f16)a[1]; o[2]=(f16)a[2]; o[3]=(f16)a[3];
    o[4]=(f16)b[0]; o[5]=(f16)b[1]; o[6]=(f16)b[2]; o[7]=(f16)b[3];
    return o;
}

// softmax weight for (l, side, c) of the gumbel channel mask
static __device__ __forceinline__ float ch_scale(const float* gum, const float* chm,
                                                 int l, int side, int c) {
    float u0 = gum[(l*2+0)*64+c], u1 = gum[(l*2+1)*64+c];
    u0 = fminf(fmaxf(u0, 1e-10f), 1.0f);
    u1 = fminf(fmaxf(u1, 1e-10f), 1.0f);
    float a0 = chm[(l*2+0)*64+c] - logf(-logf(u0));
    float a1 = chm[(l*2+1)*64+c] - logf(-logf(u1));
    float m = fmaxf(a0, a1);
    float e0 = expf(a0-m), e1 = expf(a1-m);
    float s = e0 + e1;
    return (side == 0) ? e0/s : e1/s;
}

// ------------------------------------------------- fused setup (one launch)
// region A: bpk0 pack (36864)          region B: bpkL pack w/ inline scale
// region C: wcpk pack (16384)          region D: ch -> ws_ch + out_ch (512)
// region E: guard rings of 3 fea buffers (3 x 32832)
__global__ void k_setup(const float* __restrict__ w0, const float* __restrict__ w1,
                        const float* __restrict__ w2, const float* __restrict__ w3,
                        const float* __restrict__ wc, const float* __restrict__ gum,
                        const float* __restrict__ chm,
                        float* __restrict__ ws_ch, float* __restrict__ out_ch,
                        f16* __restrict__ bpk0, f16* __restrict__ bpkL,
                        f16* __restrict__ wcpk,
                        f16* __restrict__ g1, f16* __restrict__ g2, f16* __restrict__ g3) {
    int idx = blockIdx.x * 256 + threadIdx.x;
    if (idx < 36864) {
        int j = idx & 7, lane = (idx>>3)&63, nb = (idx>>9)&3, kb = idx>>11;
        int k = kb*32 + (lane>>4)*8 + j;
        int tap = k>>6, ci = k&63;
        int co = nb*16 + (lane&15);
        bpk0[idx] = (f16)w0[(tap*64+ci)*64+co];
    } else if (idx < 36864 + 221184) {
        int i2 = idx - 36864;
        int l = i2 / 73728;               // 0..2 -> layer l+1, masks from ch[l]
        int r = i2 % 73728;
        int j = r&7, lane=(r>>3)&63, nb=(r>>9)&7, kb=r>>12;
        int k = kb*32 + (lane>>4)*8 + j;
        int tap = k>>6, ci = k&63;
        int copr = nb*16 + (lane&15);     // [0:64)=dense, [64:128)=sparse
        int co = copr & 63;
        const float* w = (l==0)? w1 : (l==1)? w2 : w3;
        float scale = ch_scale(gum, chm, l, (copr < 64) ? 0 : 1, ci);
        bpkL[i2] = (f16)(w[(tap*64+ci)*64+co] * scale);
    } else if (idx < 36864 + 221184 + 16384) {
        int i3 = idx - (36864 + 221184);
        int j=i3&7, lane=(i3>>3)&63, nb=(i3>>9)&3, kb=(i3>>11)&1, l=i3>>12;
        int k = kb*32 + (lane>>4)*8 + j;
        int n = nb*16 + (lane&15);
        wcpk[i3] = (f16)wc[(l*64+k)*64+n];
    } else if (idx < 36864 + 221184 + 16384 + 512) {
        int t = idx - (36864 + 221184 + 16384);   // (l, side*64+c) flat over 512
        int l = t >> 7, sc = t & 127;
        int side = sc >> 6, c = sc & 63;
        float v = ch_scale(gum, chm, l, side, c);
        ws_ch[(l*2+side)*64+c] = v;
        out_ch[(l*2+side)*64+c] = v;
    } else {
        int g = idx - (36864 + 221184 + 16384 + 512);
        const int TOT = 2*2052*8;
        if (g >= 3*TOT) return;
        f16* buf = (g < TOT) ? g1 : (g < 2*TOT) ? g2 : g3;
        int e = g % TOT;
        int c8 = e & 7, gg = e >> 3;
        int b = gg / 2052, r = gg % 2052;
        int hp, wp;
        if      (r < 514)  { hp = 0;        wp = r; }
        else if (r < 1028) { hp = 513;      wp = r-514; }
        else if (r < 1540) { hp = r-1027;   wp = 0; }
        else               { hp = r-1539;   wp = 513; }
        *(f16x8*)(buf + ((size_t)(b*PW+hp)*PW + wp)*64 + c8*8) = zero_f16x8();
    }
}

// ------------------------------------------------------------------- conv
// Block: 4 waves = 2 rows (wr) x 2 col-halves (wn); tile 128 px x 2 rows.
// XCD-AWARE SWIZZLE (T1): flat grid 2048; xcd = bid&7 = (b, wt) column
// strip, hb = bid>>3 walks down it -> halo + inter-layer reuse stays in the
// local XCD L2 (FETCH 139->74 MB measured, r17).
// MODE 0: raw f32 x0; fused staging (two reg batches -> cvt -> ds_write).
// MODE 1: padded f16; global_load_lds staging, phase 2 drains at kb==5.
// A/B reg-double-buffered; MFMAs under setprio(1); LDS XOR-swizzle (rule 21).
template<int MODE>
__global__ __launch_bounds__(256, 2) void k_conv(const void* __restrict__ in_, f16* __restrict__ out,
        const f16* __restrict__ bpk, const float* __restrict__ ch_l,
        const float* __restrict__ spa) {
    constexpr int NBT = (MODE==0) ? 4 : 8;
    constexpr int NF  = (MODE==0) ? 2 : 4;
    __shared__ f16 smem[4*136*64];                 // 69632 B
    const int bid = blockIdx.x;
    const int xcd = bid & 7;
    const int wt  = xcd & 3;
    const int b   = xcd >> 2;
    const int hb  = bid >> 3;                      // 0..255, contiguous per XCD
    const int h0 = hb*2;
    const int tid = threadIdx.x, lane = tid & 63, wid = tid >> 6;
    const int px0 = wt*128;
    const int sub  = lane & 7;
    const int srel = lane >> 3;
    const int cblk = sub ^ srel;                   // s&7 == srel for s=i*8+srel

    if (MODE == 0) {
        const float* inF = (const float*)in_;
        #pragma unroll
        for (int half = 0; half < 2; ++half) {
            const int J0 = half ? 9 : 0;
            const int JN = half ? 8 : 9;
            f32x4 v0[9], v1[9];
            bool ok[9];
            int dst[9];
            #pragma unroll
            for (int t = 0; t < JN; ++t) {
                int j = (J0 + t)*4 + wid;          // 0..67
                int r = j / 17, i = j % 17;
                int s = i*8 + srel;
                int hin = h0 + r - 1;
                int win = px0 + s - 1;
                ok[t] = ((unsigned)hin < HH) && ((unsigned)win < WW);
                dst[t] = r*17408 + i*1024 + lane*16;
                if (ok[t]) {
                    const f32x4* p = (const f32x4*)(inF + (((size_t)(b*HH + hin)*WW + win)*CC + cblk*8));
                    v0[t] = p[0];
                    v1[t] = p[1];
                }
            }
            #pragma unroll
            for (int t = 0; t < JN; ++t) {
                f16x8 o = ok[t] ? cvt_pair(v0[t], v1[t]) : zero_f16x8();
                if ((J0 + t)*4 + wid < 68)
                    *(f16x8*)((char*)smem + dst[t]) = o;
            }
        }
        __syncthreads();
    } else {
        const f16* inH = (const f16*)in_;
        #pragma unroll
        for (int jj = 0; jj < 9; ++jj) {
            int j = jj*4 + wid;
            if (j < 34) {
                int r = j / 17, i = j % 17;
                int s = i*8 + srel;
                const f16* src = inH + ((size_t)(b*PW + h0 + r)*PW + (px0 + s))*64 + cblk*8;
                __builtin_amdgcn_global_load_lds(
                    (const __attribute__((address_space(1))) uint32_t*)src,
                    (__attribute__((address_space(3))) uint32_t*)
                        ((char*)smem + r*17408 + i*1024),
                    16, 0, 0);
            }
        }
        __syncthreads();
        #pragma unroll
        for (int jj = 0; jj < 9; ++jj) {
            int j = 34 + jj*4 + wid;
            if (j < 68) {
                int r = j / 17, i = j % 17;
                int s = i*8 + srel;
                const f16* src = inH + ((size_t)(b*PW + h0 + r)*PW + (px0 + s))*64 + cblk*8;
                __builtin_amdgcn_global_load_lds(
                    (const __attribute__((address_space(1))) uint32_t*)src,
                    (__attribute__((address_space(3))) uint32_t*)
                        ((char*)smem + r*17408 + i*1024),
                    16, 0, 0);
            }
        }
    }

    const int wr = wid >> 1, wn = wid & 1;
    const int lrow = lane & 15, q = lane >> 4;
    const char* smw = (const char*)smem + wr*17408;   // wave's row-0 base

    int sb[8][3], po[2][3];
    #pragma unroll
    for (int dxi = 0; dxi < 3; ++dxi) {
        int m7 = (lrow + dxi) & 7;
        po[0][dxi] = ((q)     ^ m7) * 16;
        po[1][dxi] = ((4 + q) ^ m7) * 16;
        #pragma unroll
        for (int mf = 0; mf < 8; ++mf)
            sb[mf][dxi] = (mf*16 + lrow + dxi) * 128;
    }

    f32x4 acc[8][NF];
    #pragma unroll
    for (int i=0;i<8;i++)
        #pragma unroll
        for (int j=0;j<NF;j++) { f32x4 z = {0.f,0.f,0.f,0.f}; acc[i][j] = z; }

    int nbIdx[4];
    nbIdx[0]=wn*2; nbIdx[1]=wn*2+1; nbIdx[2]=wn*2+4; nbIdx[3]=wn*2+5;

    const f16* blane = bpk + (size_t)lane*8;       // + kb*NBT*512 + nb*512

    f16x8 acur[8], anxt[8], bcur[NF], bnxt[NF];
    #pragma unroll
    for (int nf=0; nf<NF; ++nf)
        bcur[nf] = *reinterpret_cast<const f16x8*>(blane + (size_t)nbIdx[nf]*512);
    #pragma unroll
    for (int mf=0; mf<8; ++mf)
        acur[mf] = *(const f16x8*)(smw + sb[mf][0] + po[0][0]);

    #pragma unroll
    for (int kb = 0; kb < 18; ++kb) {
        if (MODE == 1 && kb == 5) __syncthreads(); // rows 2,3 ready; drained under kb0-4
        if (kb < 17) {
            const int kn = kb + 1;
            const int rn = kn/6, dxin = (kn%6)/2, halfn = kn & 1;
            #pragma unroll
            for (int nf=0; nf<NF; ++nf)
                bnxt[nf] = *reinterpret_cast<const f16x8*>(blane + (size_t)(kn*NBT + nbIdx[nf])*512);
            #pragma unroll
            for (int mf=0; mf<8; ++mf)
                anxt[mf] = *(const f16x8*)(smw + rn*17408 + sb[mf][dxin] + po[halfn][dxin]);
        }
        __builtin_amdgcn_s_setprio(1);
        #pragma unroll
        for (int nf=0; nf<NF; ++nf) {
            #pragma unroll
            for (int mf=0; mf<8; ++mf)
                acc[mf][nf] = __builtin_amdgcn_mfma_f32_16x16x32_f16(acur[mf], bcur[nf], acc[mf][nf], 0,0,0);
        }
        __builtin_amdgcn_s_setprio(0);
        #pragma unroll
        for (int nf=0; nf<NF; ++nf) bcur[nf] = bnxt[nf];
        #pragma unroll
        for (int mf=0; mf<8; ++mf) acur[mf] = anxt[mf];
    }

    const float* cd = ch_l;
    const float* cs = ch_l + 64;
    const int h = h0 + wr;
    const size_t sparow = (size_t)(b*HH + h)*WW;
    const size_t outrow = (size_t)(b*PW + h + 1)*PW + 1;
    #pragma unroll
    for (int mf=0; mf<8; ++mf) {
        const int pixb = mf*16 + q*4;
        f32x4 sp4 = *(const f32x4*)(spa + sparow + px0 + pixb);
        float sp[4] = {sp4[0], sp4[1], sp4[2], sp4[3]};
        #pragma unroll
        for (int nf2=0; nf2<2; ++nf2) {
            int co = wn*32 + nf2*16 + lrow;
            float vcd = cd[co], vcs = cs[co];
            #pragma unroll
            for (int r=0; r<4; ++r) {
                float v;
                if (MODE==0) v = acc[mf][nf2][r] * (vcs*sp[r] + vcd);
                else         v = acc[mf][nf2][r] * (vcs*sp[r] + vcd) + acc[mf][nf2+2][r] * sp[r];
                v = fmaxf(v, 0.f);
                out[(outrow + px0 + pixb + r)*64 + co] = (f16)v;
            }
        }
    }
}

// --------------------------------------------------- collect (single pass)
// out[p,co] = sum_l fea_l[p,:] @ Wc_l + bias.  K = 256. Padded f16 inputs.
// XCD-ALIGNED: flat grid 4096, 128-px tiles; xcd = bid&7 = (b, wtc) decodes
// with the SAME mapping the convs used to write fea -> all four fea streams
// are local-XCD L2 hits. Wave tile 32 px x 64 co (acc 32 regs, no LDS).
// mfma(W, X, C) -> transposed C -> f32x4 (16B) stores.
__global__ __launch_bounds__(256) void k_collect_all(
        const f16* __restrict__ f0, const f16* __restrict__ f1,
        const f16* __restrict__ f2, const f16* __restrict__ f3,
        const f16* __restrict__ wcpk, const float* __restrict__ bias,
        float* __restrict__ out) {
    const int bid = blockIdx.x;                    // 4096
    const int xcd = bid & 7;
    const int wtc = xcd & 3;
    const int b   = xcd >> 2;
    const int h   = bid >> 3;                      // 0..511
    const int tid = threadIdx.x;
    const int lane = tid & 63, wid = tid >> 6;
    const int lrow = lane & 15, lk = (lane>>4)*8;
    const size_t inrow  = (size_t)(b*PW + h + 1)*PW + 1;
    const size_t outrow = (size_t)(b*HH + h)*WW;
    const int px0 = wtc*128 + wid*32;

    const f16* feas[4] = {f0, f1, f2, f3};

    f32x4 acc[2][4];
    #pragma unroll
    for (int i=0;i<2;i++)
        #pragma unroll
        for (int j=0;j<4;j++) { f32x4 z = {0.f,0.f,0.f,0.f}; acc[i][j] = z; }

    f16x8 a_cur[2], a_nxt[2];
    #pragma unroll
    for (int mf=0; mf<2; ++mf)
        a_cur[mf] = *reinterpret_cast<const f16x8*>(f0 + (inrow + px0 + mf*16 + lrow)*64 + lk);

    #pragma unroll
    for (int kb=0; kb<8; ++kb) {
        if (kb < 7) {
            const f16* fl = feas[(kb+1)>>1];
            #pragma unroll
            for (int mf=0; mf<2; ++mf)
                a_nxt[mf] = *reinterpret_cast<const f16x8*>(fl + (inrow + px0 + mf*16 + lrow)*64 + ((kb+1)&1)*32 + lk);
        }
        #pragma unroll
        for (int nf=0; nf<4; ++nf) {
            f16x8 bb = *reinterpret_cast<const f16x8*>(wcpk + ((size_t)(kb*4 + nf)*64 + lane)*8);
            #pragma unroll
            for (int mf=0; mf<2; ++mf)
                acc[mf][nf] = __builtin_amdgcn_mfma_f32_16x16x32_f16(bb, a_cur[mf], acc[mf][nf], 0,0,0);
        }
        #pragma unroll
        for (int mf=0; mf<2; ++mf) a_cur[mf] = a_nxt[mf];
    }
    const int q = lane >> 4;
    #pragma unroll
    for (int mf=0; mf<2; ++mf) {
        const int pix = px0 + mf*16 + lrow;
        float* orow = out + (outrow + pix)*CC;
        #pragma unroll
        for (int nf=0; nf<4; ++nf) {
            const int co0 = nf*16 + q*4;
            f32x4 b4 = *(const f32x4*)(bias + co0);
            *(f32x4*)(orow + co0) = acc[mf][nf] + b4;
        }
    }
}

// --------------------------------------- collect fallback (per-layer RMW)
template<bool FIRST>
__global__ __launch_bounds__(256) void k_collect(const f16* __restrict__ fea,
        const f16* __restrict__ wcpk_l, const float* __restrict__ bias,
        float* __restrict__ out) {
    const int wt = blockIdx.x, h = blockIdx.y, b = blockIdx.z;
    const int tid = threadIdx.x;
    const int lane = tid & 63, wid = tid >> 6;
    const int lrow = lane & 15, lk = (lane>>4)*8;
    const size_t inrow  = (size_t)(b*PW + h + 1)*PW + 1;
    const size_t outrow = (size_t)(b*HH + h)*WW;
    const int px0 = wt*64 + wid*16;

    f32x4 acc[4];
    #pragma unroll
    for (int j=0;j<4;j++) { f32x4 z = {0.f,0.f,0.f,0.f}; acc[j] = z; }

    #pragma unroll
    for (int kb=0; kb<2; ++kb) {
        f16x8 a = *reinterpret_cast<const f16x8*>(fea + (inrow + px0 + lrow)*64 + kb*32 + lk);
        #pragma unroll
        for (int nf=0; nf<4; ++nf) {
            f16x8 bb = *reinterpret_cast<const f16x8*>(wcpk_l + ((size_t)(kb*4 + nf)*64 + lane)*8);
            acc[nf] = __builtin_amdgcn_mfma_f32_16x16x32_f16(bb, a, acc[nf], 0,0,0);
        }
    }
    const int q = lane >> 4;
    const int pix = px0 + lrow;
    float* orow = out + (outrow + pix)*CC;
    #pragma unroll
    for (int nf=0; nf<4; ++nf) {
        const int co0 = nf*16 + q*4;
        f32x4 v = acc[nf];
        #pragma unroll
        for (int r=0;r<4;++r) {
            float x = v[r];
            if (FIRST) x += bias[co0+r];
            else       x += orow[co0+r];
            orow[co0+r] = x;
        }
    }
}

// ------------------------------------------------------------------ launch
extern "C" void kernel_launch(void* const* d_in, const int* in_sizes, int n_in,
                              void* d_out, int out_size, void* d_ws, size_t ws_size,
                              hipStream_t stream) {
    const float* x0  = (const float*)d_in[0];
    const float* spa = (const float*)d_in[1];
    const float* gum = (const float*)d_in[2];
    const float* chm = (const float*)d_in[3];
    const float* w0  = (const float*)d_in[4];
    const float* w1  = (const float*)d_in[5];
    const float* w2  = (const float*)d_in[6];
    const float* w3  = (const float*)d_in[7];
    const float* wc  = (const float*)d_in[8];
    const float* bias= (const float*)d_in[9];
    float* out = (float*)d_out;

    char* ws = (char*)d_ws;
    const size_t WBASE = (1u<<20);
    const size_t FB = 67699712ull;                 // padded fea buffer + 64KB tail
    const size_t NEED_A = WBASE + 4*FB;
    const size_t NEED_B = WBASE + 2*FB;
    if (ws_size < NEED_B) return;

    float* ws_ch = (float*)ws;
    f16* bpk0 = (f16*)(ws + 4096);
    f16* bpkL = (f16*)(ws + 4096 + 73728);
    f16* wcpk = (f16*)(ws + 4096 + 73728 + 442368);

    dim3 gcv(2048, 1, 1);   // conv: flat grid, XCD-swizzled decode in-kernel
    dim3 gcf(8, 512, 2);    // fallback collect: 64-px tiles
    const int SETUP_GRID = (36864 + 221184 + 16384 + 512 + 3*32832 + 255) / 256;

    if (ws_size >= NEED_A) {
        f16* R0 = (f16*)(ws + WBASE);              // fea4 (conv3 output)
        f16* R1 = (f16*)(ws + WBASE + FB);
        f16* R2 = (f16*)(ws + WBASE + 2*FB);
        f16* R3 = (f16*)(ws + WBASE + 3*FB);
        k_setup<<<SETUP_GRID, 256, 0, stream>>>(w0, w1, w2, w3, wc, gum, chm,
                ws_ch, out + 33554432, bpk0, bpkL, wcpk, R1, R2, R3);
        k_conv<0><<<gcv, 256, 0, stream>>>(x0, R1, bpk0,          ws_ch + 0,   spa);
        k_conv<1><<<gcv, 256, 0, stream>>>(R1, R2, bpkL + 0,      ws_ch + 128, spa);
        k_conv<1><<<gcv, 256, 0, stream>>>(R2, R3, bpkL + 73728,  ws_ch + 256, spa);
        k_conv<1><<<gcv, 256, 0, stream>>>(R3, R0, bpkL + 147456, ws_ch + 384, spa);
        k_collect_all<<<4096, 256, 0, stream>>>(R1, R2, R3, R0, wcpk, bias, out);
    } else {
        f16* P0 = (f16*)(ws + WBASE);
        f16* P1 = (f16*)(ws + WBASE + FB);
        k_setup<<<SETUP_GRID, 256, 0, stream>>>(w0, w1, w2, w3, wc, gum, chm,
                ws_ch, out + 33554432, bpk0, bpkL, wcpk, P0, P1, P0);
        k_conv<0><<<gcv, 256, 0, stream>>>(x0, P1, bpk0,          ws_ch + 0,   spa);
        k_collect<true ><<<gcf, 256, 0, stream>>>(P1, wcpk + 0,     bias, out);
        k_conv<1><<<gcv, 256, 0, stream>>>(P1, P0, bpkL + 0,      ws_ch + 128, spa);
        k_collect<false><<<gcf, 256, 0, stream>>>(P0, wcpk + 4096,  bias, out);
        k_conv<1><<<gcv, 256, 0, stream>>>(P0, P1, bpkL + 73728,  ws_ch + 256, spa);
        k_collect<false><<<gcf, 256, 0, stream>>>(P1, wcpk + 8192,  bias, out);
        k_conv<1><<<gcv, 256, 0, stream>>>(P1, P0, bpkL + 147456, ws_ch + 384, spa);
        k_collect<false><<<gcf, 256, 0, stream>>>(P0, wcpk + 12288, bias, out);
    }
}

// Round 19
// 341.870 us; speedup vs baseline: 1.0288x; 1.0288x over previous
//
#include <hip/hip_runtime.h>
#include <hip/hip_fp16.h>

#define BB 2
#define HH 512
#define WW 512
#define CC 64
#define PW 514

typedef _Float16 f16;
typedef _Float16 f16x8 __attribute__((ext_vector_type(8)));
typedef float f32x4 __attribute__((ext_vector_type(4)));

static __device__ __forceinline__ f16x8 zero_f16x8() {
    f16x8 z = {(f16)0,(f16)0,(f16)0,(f16)0,(f16)0,(f16)0,(f16)0,(f16)0};
    return z;
}

static __device__ __forceinline__ f16x8 cvt_pair(f32x4 a, f32x4 b) {
    f16x8 o;
    o[0]=(f16)a[0]; o[1]=(f16)a[1]; o[2]=(f16)a[2]; o[3]=(f16)a[3];
    o[4]=(f16)b[0]; o[5]=(f16)b[1]; o[6]=(f16)b[2]; o[7]=(f16)b[3];
    return o;
}

// softmax weight for (l, side, c) of the gumbel channel mask
static __device__ __forceinline__ float ch_scale(const float* gum, const float* chm,
                                                 int l, int side, int c) {
    float u0 = gum[(l*2+0)*64+c], u1 = gum[(l*2+1)*64+c];
    u0 = fminf(fmaxf(u0, 1e-10f), 1.0f);
    u1 = fminf(fmaxf(u1, 1e-10f), 1.0f);
    float a0 = chm[(l*2+0)*64+c] - logf(-logf(u0));
    float a1 = chm[(l*2+1)*64+c] - logf(-logf(u1));
    float m = fmaxf(a0, a1);
    float e0 = expf(a0-m), e1 = expf(a1-m);
    float s = e0 + e1;
    return (side == 0) ? e0/s : e1/s;
}

// ------------------------------------------------- fused setup (one launch)
__global__ void k_setup(const float* __restrict__ w0, const float* __restrict__ w1,
                        const float* __restrict__ w2, const float* __restrict__ w3,
                        const float* __restrict__ wc, const float* __restrict__ gum,
                        const float* __restrict__ chm,
                        float* __restrict__ ws_ch, float* __restrict__ out_ch,
                        f16* __restrict__ bpk0, f16* __restrict__ bpkL,
                        f16* __restrict__ wcpk,
                        f16* __restrict__ g1, f16* __restrict__ g2, f16* __restrict__ g3) {
    int idx = blockIdx.x * 256 + threadIdx.x;
    if (idx < 36864) {
        int j = idx & 7, lane = (idx>>3)&63, nb = (idx>>9)&3, kb = idx>>11;
        int k = kb*32 + (lane>>4)*8 + j;
        int tap = k>>6, ci = k&63;
        int co = nb*16 + (lane&15);
        bpk0[idx] = (f16)w0[(tap*64+ci)*64+co];
    } else if (idx < 36864 + 221184) {
        int i2 = idx - 36864;
        int l = i2 / 73728;               // 0..2 -> layer l+1, masks from ch[l]
        int r = i2 % 73728;
        int j = r&7, lane=(r>>3)&63, nb=(r>>9)&7, kb=r>>12;
        int k = kb*32 + (lane>>4)*8 + j;
        int tap = k>>6, ci = k&63;
        int copr = nb*16 + (lane&15);     // [0:64)=dense, [64:128)=sparse
        int co = copr & 63;
        const float* w = (l==0)? w1 : (l==1)? w2 : w3;
        float scale = ch_scale(gum, chm, l, (copr < 64) ? 0 : 1, ci);
        bpkL[i2] = (f16)(w[(tap*64+ci)*64+co] * scale);
    } else if (idx < 36864 + 221184 + 16384) {
        int i3 = idx - (36864 + 221184);
        int j=i3&7, lane=(i3>>3)&63, nb=(i3>>9)&3, kb=(i3>>11)&1, l=i3>>12;
        int k = kb*32 + (lane>>4)*8 + j;
        int n = nb*16 + (lane&15);
        wcpk[i3] = (f16)wc[(l*64+k)*64+n];
    } else if (idx < 36864 + 221184 + 16384 + 512) {
        int t = idx - (36864 + 221184 + 16384);
        int l = t >> 7, sc = t & 127;
        int side = sc >> 6, c = sc & 63;
        float v = ch_scale(gum, chm, l, side, c);
        ws_ch[(l*2+side)*64+c] = v;
        out_ch[(l*2+side)*64+c] = v;
    } else {
        int g = idx - (36864 + 221184 + 16384 + 512);
        const int TOT = 2*2052*8;
        if (g >= 3*TOT) return;
        f16* buf = (g < TOT) ? g1 : (g < 2*TOT) ? g2 : g3;
        int e = g % TOT;
        int c8 = e & 7, gg = e >> 3;
        int b = gg / 2052, r = gg % 2052;
        int hp, wp;
        if      (r < 514)  { hp = 0;        wp = r; }
        else if (r < 1028) { hp = 513;      wp = r-514; }
        else if (r < 1540) { hp = r-1027;   wp = 0; }
        else               { hp = r-1539;   wp = 513; }
        *(f16x8*)(buf + ((size_t)(b*PW+hp)*PW + wp)*64 + c8*8) = zero_f16x8();
    }
}

// ------------------------------------------------------------------- conv
// Block: 4 waves = 2 rows (wr) x 2 col-halves (wn); tile 128 px x 2 rows.
// XCD-AWARE SWIZZLE (T1): flat grid 2048; xcd = bid&7 = (b, wt) column
// strip, hb = bid>>3 walks down it -> halo + inter-layer reuse stays in the
// local XCD L2 (FETCH 139->74 MB measured, r17).
// MODE 0: raw f32 x0; fused staging (two reg batches -> cvt -> ds_write).
// MODE 1: padded f16; global_load_lds staging, phase 2 drains at kb==5.
// A/B reg-double-buffered; MFMAs under setprio(1); LDS XOR-swizzle (rule 21).
template<int MODE>
__global__ __launch_bounds__(256, 2) void k_conv(const void* __restrict__ in_, f16* __restrict__ out,
        const f16* __restrict__ bpk, const float* __restrict__ ch_l,
        const float* __restrict__ spa) {
    constexpr int NBT = (MODE==0) ? 4 : 8;
    constexpr int NF  = (MODE==0) ? 2 : 4;
    __shared__ f16 smem[4*136*64];                 // 69632 B
    const int bid = blockIdx.x;
    const int xcd = bid & 7;
    const int wt  = xcd & 3;
    const int b   = xcd >> 2;
    const int hb  = bid >> 3;                      // 0..255, contiguous per XCD
    const int h0 = hb*2;
    const int tid = threadIdx.x, lane = tid & 63, wid = tid >> 6;
    const int px0 = wt*128;
    const int sub  = lane & 7;
    const int srel = lane >> 3;
    const int cblk = sub ^ srel;                   // s&7 == srel for s=i*8+srel

    if (MODE == 0) {
        const float* inF = (const float*)in_;
        #pragma unroll
        for (int half = 0; half < 2; ++half) {
            const int J0 = half ? 9 : 0;
            const int JN = half ? 8 : 9;
            f32x4 v0[9], v1[9];
            bool ok[9];
            int dst[9];
            #pragma unroll
            for (int t = 0; t < JN; ++t) {
                int j = (J0 + t)*4 + wid;          // 0..67
                int r = j / 17, i = j % 17;
                int s = i*8 + srel;
                int hin = h0 + r - 1;
                int win = px0 + s - 1;
                ok[t] = ((unsigned)hin < HH) && ((unsigned)win < WW);
                dst[t] = r*17408 + i*1024 + lane*16;
                if (ok[t]) {
                    const f32x4* p = (const f32x4*)(inF + (((size_t)(b*HH + hin)*WW + win)*CC + cblk*8));
                    v0[t] = p[0];
                    v1[t] = p[1];
                }
            }
            #pragma unroll
            for (int t = 0; t < JN; ++t) {
                f16x8 o = ok[t] ? cvt_pair(v0[t], v1[t]) : zero_f16x8();
                if ((J0 + t)*4 + wid < 68)
                    *(f16x8*)((char*)smem + dst[t]) = o;
            }
        }
        __syncthreads();
    } else {
        const f16* inH = (const f16*)in_;
        #pragma unroll
        for (int jj = 0; jj < 9; ++jj) {
            int j = jj*4 + wid;
            if (j < 34) {
                int r = j / 17, i = j % 17;
                int s = i*8 + srel;
                const f16* src = inH + ((size_t)(b*PW + h0 + r)*PW + (px0 + s))*64 + cblk*8;
                __builtin_amdgcn_global_load_lds(
                    (const __attribute__((address_space(1))) uint32_t*)src,
                    (__attribute__((address_space(3))) uint32_t*)
                        ((char*)smem + r*17408 + i*1024),
                    16, 0, 0);
            }
        }
        __syncthreads();
        #pragma unroll
        for (int jj = 0; jj < 9; ++jj) {
            int j = 34 + jj*4 + wid;
            if (j < 68) {
                int r = j / 17, i = j % 17;
                int s = i*8 + srel;
                const f16* src = inH + ((size_t)(b*PW + h0 + r)*PW + (px0 + s))*64 + cblk*8;
                __builtin_amdgcn_global_load_lds(
                    (const __attribute__((address_space(1))) uint32_t*)src,
                    (__attribute__((address_space(3))) uint32_t*)
                        ((char*)smem + r*17408 + i*1024),
                    16, 0, 0);
            }
        }
    }

    const int wr = wid >> 1, wn = wid & 1;
    const int lrow = lane & 15, q = lane >> 4;
    const char* smw = (const char*)smem + wr*17408;   // wave's row-0 base

    int sb[8][3], po[2][3];
    #pragma unroll
    for (int dxi = 0; dxi < 3; ++dxi) {
        int m7 = (lrow + dxi) & 7;
        po[0][dxi] = ((q)     ^ m7) * 16;
        po[1][dxi] = ((4 + q) ^ m7) * 16;
        #pragma unroll
        for (int mf = 0; mf < 8; ++mf)
            sb[mf][dxi] = (mf*16 + lrow + dxi) * 128;
    }

    f32x4 acc[8][NF];
    #pragma unroll
    for (int i=0;i<8;i++)
        #pragma unroll
        for (int j=0;j<NF;j++) { f32x4 z = {0.f,0.f,0.f,0.f}; acc[i][j] = z; }

    int nbIdx[4];
    nbIdx[0]=wn*2; nbIdx[1]=wn*2+1; nbIdx[2]=wn*2+4; nbIdx[3]=wn*2+5;

    const f16* blane = bpk + (size_t)lane*8;       // + kb*NBT*512 + nb*512

    f16x8 acur[8], anxt[8], bcur[NF], bnxt[NF];
    #pragma unroll
    for (int nf=0; nf<NF; ++nf)
        bcur[nf] = *reinterpret_cast<const f16x8*>(blane + (size_t)nbIdx[nf]*512);
    #pragma unroll
    for (int mf=0; mf<8; ++mf)
        acur[mf] = *(const f16x8*)(smw + sb[mf][0] + po[0][0]);

    #pragma unroll
    for (int kb = 0; kb < 18; ++kb) {
        if (MODE == 1 && kb == 5) __syncthreads(); // rows 2,3 ready; drained under kb0-4
        if (kb < 17) {
            const int kn = kb + 1;
            const int rn = kn/6, dxin = (kn%6)/2, halfn = kn & 1;
            #pragma unroll
            for (int nf=0; nf<NF; ++nf)
                bnxt[nf] = *reinterpret_cast<const f16x8*>(blane + (size_t)(kn*NBT + nbIdx[nf])*512);
            #pragma unroll
            for (int mf=0; mf<8; ++mf)
                anxt[mf] = *(const f16x8*)(smw + rn*17408 + sb[mf][dxin] + po[halfn][dxin]);
        }
        __builtin_amdgcn_s_setprio(1);
        #pragma unroll
        for (int nf=0; nf<NF; ++nf) {
            #pragma unroll
            for (int mf=0; mf<8; ++mf)
                acc[mf][nf] = __builtin_amdgcn_mfma_f32_16x16x32_f16(acur[mf], bcur[nf], acc[mf][nf], 0,0,0);
        }
        __builtin_amdgcn_s_setprio(0);
        #pragma unroll
        for (int nf=0; nf<NF; ++nf) bcur[nf] = bnxt[nf];
        #pragma unroll
        for (int mf=0; mf<8; ++mf) acur[mf] = anxt[mf];
    }

    const float* cd = ch_l;
    const float* cs = ch_l + 64;
    const int h = h0 + wr;
    const size_t sparow = (size_t)(b*HH + h)*WW;
    const size_t outrow = (size_t)(b*PW + h + 1)*PW + 1;
    #pragma unroll
    for (int mf=0; mf<8; ++mf) {
        const int pixb = mf*16 + q*4;
        f32x4 sp4 = *(const f32x4*)(spa + sparow + px0 + pixb);
        float sp[4] = {sp4[0], sp4[1], sp4[2], sp4[3]};
        #pragma unroll
        for (int nf2=0; nf2<2; ++nf2) {
            int co = wn*32 + nf2*16 + lrow;
            float vcd = cd[co], vcs = cs[co];
            #pragma unroll
            for (int r=0; r<4; ++r) {
                float v;
                if (MODE==0) v = acc[mf][nf2][r] * (vcs*sp[r] + vcd);
                else         v = acc[mf][nf2][r] * (vcs*sp[r] + vcd) + acc[mf][nf2+2][r] * sp[r];
                v = fmaxf(v, 0.f);
                out[(outrow + px0 + pixb + r)*64 + co] = (f16)v;
            }
        }
    }
}

// --------------------------------------------------- collect (single pass)
// out[p,co] = sum_l fea_l[p,:] @ Wc_l + bias.  K = 256. Padded f16 inputs.
// Round-17 form (best measured): grid (2,512,2), wave 64 px, acc[4][4],
// mfma(W, X, C) -> transposed C -> f32x4 (16B) plain stores.
__global__ __launch_bounds__(256) void k_collect_all(
        const f16* __restrict__ f0, const f16* __restrict__ f1,
        const f16* __restrict__ f2, const f16* __restrict__ f3,
        const f16* __restrict__ wcpk, const float* __restrict__ bias,
        float* __restrict__ out) {
    const int wt = blockIdx.x, h = blockIdx.y, b = blockIdx.z;
    const int tid = threadIdx.x;
    const int lane = tid & 63, wid = tid >> 6;
    const int lrow = lane & 15, lk = (lane>>4)*8;
    const size_t inrow  = (size_t)(b*PW + h + 1)*PW + 1;
    const size_t outrow = (size_t)(b*HH + h)*WW;
    const int px0 = wt*256 + wid*64;

    const f16* feas[4] = {f0, f1, f2, f3};

    f32x4 acc[4][4];
    #pragma unroll
    for (int i=0;i<4;i++)
        #pragma unroll
        for (int j=0;j<4;j++) { f32x4 z = {0.f,0.f,0.f,0.f}; acc[i][j] = z; }

    #pragma unroll
    for (int kb=0; kb<8; ++kb) {
        const f16* fl = feas[kb>>1];
        f16x8 a[4];
        #pragma unroll
        for (int mf=0; mf<4; ++mf)
            a[mf] = *reinterpret_cast<const f16x8*>(fl + (inrow + px0 + mf*16 + lrow)*64 + (kb&1)*32 + lk);
        #pragma unroll
        for (int nf=0; nf<4; ++nf) {
            f16x8 bb = *reinterpret_cast<const f16x8*>(wcpk + ((size_t)(kb*4 + nf)*64 + lane)*8);
            #pragma unroll
            for (int mf=0; mf<4; ++mf)
                acc[mf][nf] = __builtin_amdgcn_mfma_f32_16x16x32_f16(bb, a[mf], acc[mf][nf], 0,0,0);
        }
    }
    const int q = lane >> 4;
    #pragma unroll
    for (int mf=0; mf<4; ++mf) {
        const int pix = px0 + mf*16 + lrow;
        float* orow = out + (outrow + pix)*CC;
        #pragma unroll
        for (int nf=0; nf<4; ++nf) {
            const int co0 = nf*16 + q*4;
            f32x4 b4 = *(const f32x4*)(bias + co0);
            *(f32x4*)(orow + co0) = acc[mf][nf] + b4;
        }
    }
}

// --------------------------------------- collect fallback (per-layer RMW)
template<bool FIRST>
__global__ __launch_bounds__(256) void k_collect(const f16* __restrict__ fea,
        const f16* __restrict__ wcpk_l, const float* __restrict__ bias,
        float* __restrict__ out) {
    const int wt = blockIdx.x, h = blockIdx.y, b = blockIdx.z;
    const int tid = threadIdx.x;
    const int lane = tid & 63, wid = tid >> 6;
    const int lrow = lane & 15, lk = (lane>>4)*8;
    const size_t inrow  = (size_t)(b*PW + h + 1)*PW + 1;
    const size_t outrow = (size_t)(b*HH + h)*WW;
    const int px0 = wt*64 + wid*16;

    f32x4 acc[4];
    #pragma unroll
    for (int j=0;j<4;j++) { f32x4 z = {0.f,0.f,0.f,0.f}; acc[j] = z; }

    #pragma unroll
    for (int kb=0; kb<2; ++kb) {
        f16x8 a = *reinterpret_cast<const f16x8*>(fea + (inrow + px0 + lrow)*64 + kb*32 + lk);
        #pragma unroll
        for (int nf=0; nf<4; ++nf) {
            f16x8 bb = *reinterpret_cast<const f16x8*>(wcpk_l + ((size_t)(kb*4 + nf)*64 + lane)*8);
            acc[nf] = __builtin_amdgcn_mfma_f32_16x16x32_f16(bb, a, acc[nf], 0,0,0);
        }
    }
    const int q = lane >> 4;
    const int pix = px0 + lrow;
    float* orow = out + (outrow + pix)*CC;
    #pragma unroll
    for (int nf=0; nf<4; ++nf) {
        const int co0 = nf*16 + q*4;
        f32x4 v = acc[nf];
        #pragma unroll
        for (int r=0;r<4;++r) {
            float x = v[r];
            if (FIRST) x += bias[co0+r];
            else       x += orow[co0+r];
            orow[co0+r] = x;
        }
    }
}

// ------------------------------------------------------------------ launch
extern "C" void kernel_launch(void* const* d_in, const int* in_sizes, int n_in,
                              void* d_out, int out_size, void* d_ws, size_t ws_size,
                              hipStream_t stream) {
    const float* x0  = (const float*)d_in[0];
    const float* spa = (const float*)d_in[1];
    const float* gum = (const float*)d_in[2];
    const float* chm = (const float*)d_in[3];
    const float* w0  = (const float*)d_in[4];
    const float* w1  = (const float*)d_in[5];
    const float* w2  = (const float*)d_in[6];
    const float* w3  = (const float*)d_in[7];
    const float* wc  = (const float*)d_in[8];
    const float* bias= (const float*)d_in[9];
    float* out = (float*)d_out;

    char* ws = (char*)d_ws;
    const size_t WBASE = (1u<<20);
    const size_t FB = 67699712ull;                 // padded fea buffer + 64KB tail
    const size_t NEED_A = WBASE + 4*FB;
    const size_t NEED_B = WBASE + 2*FB;
    if (ws_size < NEED_B) return;

    float* ws_ch = (float*)ws;
    f16* bpk0 = (f16*)(ws + 4096);
    f16* bpkL = (f16*)(ws + 4096 + 73728);
    f16* wcpk = (f16*)(ws + 4096 + 73728 + 442368);

    dim3 gcv(2048, 1, 1);   // conv: flat grid, XCD-swizzled decode in-kernel
    dim3 gca(2, 512, 2);    // collect_all: 256-px tiles
    dim3 gcf(8, 512, 2);    // fallback collect: 64-px tiles
    const int SETUP_GRID = (36864 + 221184 + 16384 + 512 + 3*32832 + 255) / 256;

    if (ws_size >= NEED_A) {
        f16* R0 = (f16*)(ws + WBASE);              // fea4 (conv3 output)
        f16* R1 = (f16*)(ws + WBASE + FB);
        f16* R2 = (f16*)(ws + WBASE + 2*FB);
        f16* R3 = (f16*)(ws + WBASE + 3*FB);
        k_setup<<<SETUP_GRID, 256, 0, stream>>>(w0, w1, w2, w3, wc, gum, chm,
                ws_ch, out + 33554432, bpk0, bpkL, wcpk, R1, R2, R3);
        k_conv<0><<<gcv, 256, 0, stream>>>(x0, R1, bpk0,          ws_ch + 0,   spa);
        k_conv<1><<<gcv, 256, 0, stream>>>(R1, R2, bpkL + 0,      ws_ch + 128, spa);
        k_conv<1><<<gcv, 256, 0, stream>>>(R2, R3, bpkL + 73728,  ws_ch + 256, spa);
        k_conv<1><<<gcv, 256, 0, stream>>>(R3, R0, bpkL + 147456, ws_ch + 384, spa);
        k_collect_all<<<gca, 256, 0, stream>>>(R1, R2, R3, R0, wcpk, bias, out);
    } else {
        f16* P0 = (f16*)(ws + WBASE);
        f16* P1 = (f16*)(ws + WBASE + FB);
        k_setup<<<SETUP_GRID, 256, 0, stream>>>(w0, w1, w2, w3, wc, gum, chm,
                ws_ch, out + 33554432, bpk0, bpkL, wcpk, P0, P1, P0);
        k_conv<0><<<gcv, 256, 0, stream>>>(x0, P1, bpk0,          ws_ch + 0,   spa);
        k_collect<true ><<<gcf, 256, 0, stream>>>(P1, wcpk + 0,     bias, out);
        k_conv<1><<<gcv, 256, 0, stream>>>(P1, P0, bpkL + 0,      ws_ch + 128, spa);
        k_collect<false><<<gcf, 256, 0, stream>>>(P0, wcpk + 4096,  bias, out);
        k_conv<1><<<gcv, 256, 0, stream>>>(P0, P1, bpkL + 73728,  ws_ch + 256, spa);
        k_collect<false><<<gcf, 256, 0, stream>>>(P1, wcpk + 8192,  bias, out);
        k_conv<1><<<gcv, 256, 0, stream>>>(P1, P0, bpkL + 147456, ws_ch + 384, spa);
        k_collect<false><<<gcf, 256, 0, stream>>>(P0, wcpk + 12288, bias, out);
    }
}

// Round 20
// 320.407 us; speedup vs baseline: 1.0977x; 1.0670x over previous
//
#include <hip/hip_runtime.h>
#include <hip/hip_fp16.h>

#define BB 2
#define HH 512
#define WW 512
#define CC 64
#define PW 514

typedef _Float16 f16;
typedef _Float16 f16x8 __attribute__((ext_vector_type(8)));
typedef _Float16 f16x4 __attribute__((ext_vector_type(4)));
typedef float f32x4 __attribute__((ext_vector_type(4)));

static __device__ __forceinline__ f16x8 zero_f16x8() {
    f16x8 z = {(f16)0,(f16)0,(f16)0,(f16)0,(f16)0,(f16)0,(f16)0,(f16)0};
    return z;
}

static __device__ __forceinline__ f16x8 cvt_pair(f32x4 a, f32x4 b) {
    f16x8 o;
    o[0]=(f16)a[0]; o[1]=(f16)a[1]; o[2]=(f16)a[2]; o[3]=(f16)a[3];
    o[4]=(f16)b[0]; o[5]=(f16)b[1]; o[6]=(f16)b[2]; o[7]=(f16)b[3];
    return o;
}

// softmax weight for (l, side, c) of the gumbel channel mask
static __device__ __forceinline__ float ch_scale(const float* gum, const float* chm,
                                                 int l, int side, int c) {
    float u0 = gum[(l*2+0)*64+c], u1 = gum[(l*2+1)*64+c];
    u0 = fminf(fmaxf(u0, 1e-10f), 1.0f);
    u1 = fminf(fmaxf(u1, 1e-10f), 1.0f);
    float a0 = chm[(l*2+0)*64+c] - logf(-logf(u0));
    float a1 = chm[(l*2+1)*64+c] - logf(-logf(u1));
    float m = fmaxf(a0, a1);
    float e0 = expf(a0-m), e1 = expf(a1-m);
    float s = e0 + e1;
    return (side == 0) ? e0/s : e1/s;
}

// ------------------------------------------------- fused setup (one launch)
__global__ void k_setup(const float* __restrict__ w0, const float* __restrict__ w1,
                        const float* __restrict__ w2, const float* __restrict__ w3,
                        const float* __restrict__ wc, const float* __restrict__ gum,
                        const float* __restrict__ chm,
                        float* __restrict__ ws_ch, float* __restrict__ out_ch,
                        f16* __restrict__ bpk0, f16* __restrict__ bpkL,
                        f16* __restrict__ wcpk,
                        f16* __restrict__ g1, f16* __restrict__ g2, f16* __restrict__ g3) {
    int idx = blockIdx.x * 256 + threadIdx.x;
    if (idx < 36864) {
        int j = idx & 7, lane = (idx>>3)&63, nb = (idx>>9)&3, kb = idx>>11;
        int k = kb*32 + (lane>>4)*8 + j;
        int tap = k>>6, ci = k&63;
        int co = nb*16 + (lane&15);
        bpk0[idx] = (f16)w0[(tap*64+ci)*64+co];
    } else if (idx < 36864 + 221184) {
        int i2 = idx - 36864;
        int l = i2 / 73728;               // 0..2 -> layer l+1, masks from ch[l]
        int r = i2 % 73728;
        int j = r&7, lane=(r>>3)&63, nb=(r>>9)&7, kb=r>>12;
        int k = kb*32 + (lane>>4)*8 + j;
        int tap = k>>6, ci = k&63;
        int copr = nb*16 + (lane&15);     // [0:64)=dense, [64:128)=sparse
        int co = copr & 63;
        const float* w = (l==0)? w1 : (l==1)? w2 : w3;
        float scale = ch_scale(gum, chm, l, (copr < 64) ? 0 : 1, ci);
        bpkL[i2] = (f16)(w[(tap*64+ci)*64+co] * scale);
    } else if (idx < 36864 + 221184 + 16384) {
        int i3 = idx - (36864 + 221184);
        int j=i3&7, lane=(i3>>3)&63, nb=(i3>>9)&3, kb=(i3>>11)&1, l=i3>>12;
        int k = kb*32 + (lane>>4)*8 + j;
        int n = nb*16 + (lane&15);
        wcpk[i3] = (f16)wc[(l*64+k)*64+n];
    } else if (idx < 36864 + 221184 + 16384 + 512) {
        int t = idx - (36864 + 221184 + 16384);
        int l = t >> 7, sc = t & 127;
        int side = sc >> 6, c = sc & 63;
        float v = ch_scale(gum, chm, l, side, c);
        ws_ch[(l*2+side)*64+c] = v;
        out_ch[(l*2+side)*64+c] = v;
    } else {
        int g = idx - (36864 + 221184 + 16384 + 512);
        const int TOT = 2*2052*8;
        if (g >= 3*TOT) return;
        f16* buf = (g < TOT) ? g1 : (g < 2*TOT) ? g2 : g3;
        int e = g % TOT;
        int c8 = e & 7, gg = e >> 3;
        int b = gg / 2052, r = gg % 2052;
        int hp, wp;
        if      (r < 514)  { hp = 0;        wp = r; }
        else if (r < 1028) { hp = 513;      wp = r-514; }
        else if (r < 1540) { hp = r-1027;   wp = 0; }
        else               { hp = r-1539;   wp = 513; }
        *(f16x8*)(buf + ((size_t)(b*PW+hp)*PW + wp)*64 + c8*8) = zero_f16x8();
    }
}

// ------------------------------------------------------------------- conv
// Block: 4 waves = 2 rows (wr) x 2 col-halves (wn); tile 128 px x 2 rows.
// XCD-AWARE SWIZZLE (T1): flat grid 2048; xcd = bid&7 = (b, wt) strip.
// MODE 0: raw f32 x0 -> fea1 (fused cvt staging).
// MODE 1: padded f16 -> padded f16 (global_load_lds staging, 2 phases).
// MODE 2: layer-3 conv FUSED with collect: conv result tile kept in LDS
//   (transposed-C epilogue -> vectorized f16x4 ds_writes, XOR-swizzled),
//   then phase 2 computes out[p,:] = sum_l fea_l[p,:] @ Wc_l + bias with
//   fea1..3 from global and fea4 from the LDS tile. fea4 never hits HBM.
// A/B reg-double-buffered; MFMAs under setprio(1); LDS XOR-swizzle (rule 21).
template<int MODE>
__global__ __launch_bounds__(256, 2) void k_conv(const void* __restrict__ in_, f16* __restrict__ out,
        const f16* __restrict__ bpk, const float* __restrict__ ch_l,
        const float* __restrict__ spa,
        const f16* __restrict__ fA, const f16* __restrict__ fB,
        const f16* __restrict__ wcpk, const float* __restrict__ bias,
        float* __restrict__ outF) {
    constexpr int NBT = (MODE==0) ? 4 : 8;
    constexpr int NF  = (MODE==0) ? 2 : 4;
    __shared__ f16 smem[4*136*64];                 // 69632 B (P tile reuses [0,32768))
    const int bid = blockIdx.x;
    const int xcd = bid & 7;
    const int wt  = xcd & 3;
    const int b   = xcd >> 2;
    const int hb  = bid >> 3;                      // 0..255, contiguous per XCD
    const int h0 = hb*2;
    const int tid = threadIdx.x, lane = tid & 63, wid = tid >> 6;
    const int px0 = wt*128;
    const int sub  = lane & 7;
    const int srel = lane >> 3;
    const int cblk = sub ^ srel;                   // s&7 == srel for s=i*8+srel

    if (MODE == 0) {
        const float* inF = (const float*)in_;
        #pragma unroll
        for (int half = 0; half < 2; ++half) {
            const int J0 = half ? 9 : 0;
            const int JN = half ? 8 : 9;
            f32x4 v0[9], v1[9];
            bool ok[9];
            int dst[9];
            #pragma unroll
            for (int t = 0; t < JN; ++t) {
                int j = (J0 + t)*4 + wid;          // 0..67
                int r = j / 17, i = j % 17;
                int s = i*8 + srel;
                int hin = h0 + r - 1;
                int win = px0 + s - 1;
                ok[t] = ((unsigned)hin < HH) && ((unsigned)win < WW);
                dst[t] = r*17408 + i*1024 + lane*16;
                if (ok[t]) {
                    const f32x4* p = (const f32x4*)(inF + (((size_t)(b*HH + hin)*WW + win)*CC + cblk*8));
                    v0[t] = p[0];
                    v1[t] = p[1];
                }
            }
            #pragma unroll
            for (int t = 0; t < JN; ++t) {
                f16x8 o = ok[t] ? cvt_pair(v0[t], v1[t]) : zero_f16x8();
                if ((J0 + t)*4 + wid < 68)
                    *(f16x8*)((char*)smem + dst[t]) = o;
            }
        }
        __syncthreads();
    } else {
        const f16* inH = (const f16*)in_;
        #pragma unroll
        for (int jj = 0; jj < 9; ++jj) {
            int j = jj*4 + wid;
            if (j < 34) {
                int r = j / 17, i = j % 17;
                int s = i*8 + srel;
                const f16* src = inH + ((size_t)(b*PW + h0 + r)*PW + (px0 + s))*64 + cblk*8;
                __builtin_amdgcn_global_load_lds(
                    (const __attribute__((address_space(1))) uint32_t*)src,
                    (__attribute__((address_space(3))) uint32_t*)
                        ((char*)smem + r*17408 + i*1024),
                    16, 0, 0);
            }
        }
        __syncthreads();
        #pragma unroll
        for (int jj = 0; jj < 9; ++jj) {
            int j = 34 + jj*4 + wid;
            if (j < 68) {
                int r = j / 17, i = j % 17;
                int s = i*8 + srel;
                const f16* src = inH + ((size_t)(b*PW + h0 + r)*PW + (px0 + s))*64 + cblk*8;
                __builtin_amdgcn_global_load_lds(
                    (const __attribute__((address_space(1))) uint32_t*)src,
                    (__attribute__((address_space(3))) uint32_t*)
                        ((char*)smem + r*17408 + i*1024),
                    16, 0, 0);
            }
        }
    }

    const int wr = wid >> 1, wn = wid & 1;
    const int lrow = lane & 15, q = lane >> 4;
    const char* smw = (const char*)smem + wr*17408;   // wave's row-0 base

    int sb[8][3], po[2][3];
    #pragma unroll
    for (int dxi = 0; dxi < 3; ++dxi) {
        int m7 = (lrow + dxi) & 7;
        po[0][dxi] = ((q)     ^ m7) * 16;
        po[1][dxi] = ((4 + q) ^ m7) * 16;
        #pragma unroll
        for (int mf = 0; mf < 8; ++mf)
            sb[mf][dxi] = (mf*16 + lrow + dxi) * 128;
    }

    f32x4 acc[8][NF];
    #pragma unroll
    for (int i=0;i<8;i++)
        #pragma unroll
        for (int j=0;j<NF;j++) { f32x4 z = {0.f,0.f,0.f,0.f}; acc[i][j] = z; }

    int nbIdx[4];
    nbIdx[0]=wn*2; nbIdx[1]=wn*2+1; nbIdx[2]=wn*2+4; nbIdx[3]=wn*2+5;

    const f16* blane = bpk + (size_t)lane*8;       // + kb*NBT*512 + nb*512

    f16x8 acur[8], anxt[8], bcur[NF], bnxt[NF];
    #pragma unroll
    for (int nf=0; nf<NF; ++nf)
        bcur[nf] = *reinterpret_cast<const f16x8*>(blane + (size_t)nbIdx[nf]*512);
    #pragma unroll
    for (int mf=0; mf<8; ++mf)
        acur[mf] = *(const f16x8*)(smw + sb[mf][0] + po[0][0]);

    #pragma unroll
    for (int kb = 0; kb < 18; ++kb) {
        if (MODE >= 1 && kb == 5) __syncthreads(); // rows 2,3 ready; drained under kb0-4
        if (kb < 17) {
            const int kn = kb + 1;
            const int rn = kn/6, dxin = (kn%6)/2, halfn = kn & 1;
            #pragma unroll
            for (int nf=0; nf<NF; ++nf)
                bnxt[nf] = *reinterpret_cast<const f16x8*>(blane + (size_t)(kn*NBT + nbIdx[nf])*512);
            #pragma unroll
            for (int mf=0; mf<8; ++mf)
                anxt[mf] = *(const f16x8*)(smw + rn*17408 + sb[mf][dxin] + po[halfn][dxin]);
        }
        __builtin_amdgcn_s_setprio(1);
        #pragma unroll
        for (int nf=0; nf<NF; ++nf) {
            #pragma unroll
            for (int mf=0; mf<8; ++mf) {
                if (MODE == 2)
                    acc[mf][nf] = __builtin_amdgcn_mfma_f32_16x16x32_f16(bcur[nf], acur[mf], acc[mf][nf], 0,0,0);
                else
                    acc[mf][nf] = __builtin_amdgcn_mfma_f32_16x16x32_f16(acur[mf], bcur[nf], acc[mf][nf], 0,0,0);
            }
        }
        __builtin_amdgcn_s_setprio(0);
        #pragma unroll
        for (int nf=0; nf<NF; ++nf) bcur[nf] = bnxt[nf];
        #pragma unroll
        for (int mf=0; mf<8; ++mf) acur[mf] = anxt[mf];
    }

    const float* cd = ch_l;
    const float* cs = ch_l + 64;
    const int h = h0 + wr;
    const size_t sparow = (size_t)(b*HH + h)*WW;

    if (MODE != 2) {
        const size_t outrow = (size_t)(b*PW + h + 1)*PW + 1;
        #pragma unroll
        for (int mf=0; mf<8; ++mf) {
            const int pixb = mf*16 + q*4;
            f32x4 sp4 = *(const f32x4*)(spa + sparow + px0 + pixb);
            float sp[4] = {sp4[0], sp4[1], sp4[2], sp4[3]};
            #pragma unroll
            for (int nf2=0; nf2<2; ++nf2) {
                int co = wn*32 + nf2*16 + lrow;
                float vcd = cd[co], vcs = cs[co];
                #pragma unroll
                for (int r=0; r<4; ++r) {
                    float v;
                    if (MODE==0) v = acc[mf][nf2][r] * (vcs*sp[r] + vcd);
                    else         v = acc[mf][nf2][r] * (vcs*sp[r] + vcd) + acc[mf][nf2+2][r] * sp[r];
                    v = fmaxf(v, 0.f);
                    out[(outrow + px0 + pixb + r)*64 + co] = (f16)v;
                }
            }
        }
        return;
    }

    // ---------------- MODE 2: epilogue -> LDS P tile, then fused collect ----
    __syncthreads();                               // staged A fully consumed
    {
        // Transposed C: per (mf,nf2) lane holds co = wn*32+nf2*16+q*4..+3 at
        // pixel = mf*16 + lrow. P layout: [row][pix][ci] f16, 16B chunk index
        // XOR-swizzled with (pix&7).
        #pragma unroll
        for (int mf=0; mf<8; ++mf) {
            const int pix = mf*16 + lrow;
            const float sp = spa[sparow + px0 + pix];
            #pragma unroll
            for (int nf2=0; nf2<2; ++nf2) {
                const int co0 = wn*32 + nf2*16 + q*4;
                f32x4 cd4 = *(const f32x4*)(cd + co0);
                f32x4 cs4 = *(const f32x4*)(cs + co0);
                f16x4 o;
                #pragma unroll
                for (int r=0; r<4; ++r) {
                    float v = acc[mf][nf2][r] * (cs4[r]*sp + cd4[r]) + acc[mf][nf2+2][r] * sp;
                    o[r] = (f16)fmaxf(v, 0.f);
                }
                const int chunk = co0 >> 3;        // wn*4 + nf2*2 + (q>>1)
                const int addr = (wr*128 + pix)*128 + ((chunk ^ (pix & 7))*16) + (q & 1)*8;
                *(f16x4*)((char*)smem + addr) = o;
            }
        }
    }
    __syncthreads();                               // P tile complete

    {
        const int row2 = wid >> 1;                 // waves 0,1 -> row 0; 2,3 -> row 1
        const int pxc  = (wid & 1)*64;             // wave's 64-px half
        const int h2 = h0 + row2;
        const size_t inrow2  = (size_t)(b*PW + h2 + 1)*PW + 1;
        const size_t outrow2 = (size_t)(b*HH + h2)*WW;
        const int lk = q*8;
        const f16* inH = (const f16*)in_;          // fea3

        f32x4 acc2[4][4];
        #pragma unroll
        for (int i=0;i<4;i++)
            #pragma unroll
            for (int j=0;j<4;j++) { f32x4 z = {0.f,0.f,0.f,0.f}; acc2[i][j] = z; }

        #pragma unroll
        for (int kb=0; kb<8; ++kb) {
            f16x8 a[4];
            if (kb < 6) {
                const f16* fl = (kb < 2) ? fA : (kb < 4) ? fB : inH;
                #pragma unroll
                for (int mf2=0; mf2<4; ++mf2)
                    a[mf2] = *reinterpret_cast<const f16x8*>(fl + (inrow2 + px0 + pxc + mf2*16 + lrow)*64 + (kb&1)*32 + lk);
            } else {
                const int chunk = (kb-6)*4 + q;
                #pragma unroll
                for (int mf2=0; mf2<4; ++mf2) {
                    const int pixl = pxc + mf2*16 + lrow;
                    a[mf2] = *(const f16x8*)((const char*)smem + (row2*128 + pixl)*128 + ((chunk ^ (lrow & 7))*16));
                }
            }
            #pragma unroll
            for (int nf=0; nf<4; ++nf) {
                f16x8 bb = *reinterpret_cast<const f16x8*>(wcpk + ((size_t)(kb*4 + nf)*64 + lane)*8);
                #pragma unroll
                for (int mf2=0; mf2<4; ++mf2)
                    acc2[mf2][nf] = __builtin_amdgcn_mfma_f32_16x16x32_f16(bb, a[mf2], acc2[mf2][nf], 0,0,0);
            }
        }
        #pragma unroll
        for (int mf2=0; mf2<4; ++mf2) {
            const int pixg = px0 + pxc + mf2*16 + lrow;
            float* orow = outF + (outrow2 + pixg)*CC;
            #pragma unroll
            for (int nf=0; nf<4; ++nf) {
                const int co0 = nf*16 + q*4;
                f32x4 b4 = *(const f32x4*)(bias + co0);
                *(f32x4*)(orow + co0) = acc2[mf2][nf] + b4;
            }
        }
    }
}

// --------------------------------------- collect fallback (per-layer RMW)
template<bool FIRST>
__global__ __launch_bounds__(256) void k_collect(const f16* __restrict__ fea,
        const f16* __restrict__ wcpk_l, const float* __restrict__ bias,
        float* __restrict__ out) {
    const int wt = blockIdx.x, h = blockIdx.y, b = blockIdx.z;
    const int tid = threadIdx.x;
    const int lane = tid & 63, wid = tid >> 6;
    const int lrow = lane & 15, lk = (lane>>4)*8;
    const size_t inrow  = (size_t)(b*PW + h + 1)*PW + 1;
    const size_t outrow = (size_t)(b*HH + h)*WW;
    const int px0 = wt*64 + wid*16;

    f32x4 acc[4];
    #pragma unroll
    for (int j=0;j<4;j++) { f32x4 z = {0.f,0.f,0.f,0.f}; acc[j] = z; }

    #pragma unroll
    for (int kb=0; kb<2; ++kb) {
        f16x8 a = *reinterpret_cast<const f16x8*>(fea + (inrow + px0 + lrow)*64 + kb*32 + lk);
        #pragma unroll
        for (int nf=0; nf<4; ++nf) {
            f16x8 bb = *reinterpret_cast<const f16x8*>(wcpk_l + ((size_t)(kb*4 + nf)*64 + lane)*8);
            acc[nf] = __builtin_amdgcn_mfma_f32_16x16x32_f16(bb, a, acc[nf], 0,0,0);
        }
    }
    const int q = lane >> 4;
    const int pix = px0 + lrow;
    float* orow = out + (outrow + pix)*CC;
    #pragma unroll
    for (int nf=0; nf<4; ++nf) {
        const int co0 = nf*16 + q*4;
        f32x4 v = acc[nf];
        #pragma unroll
        for (int r=0;r<4;++r) {
            float x = v[r];
            if (FIRST) x += bias[co0+r];
            else       x += orow[co0+r];
            orow[co0+r] = x;
        }
    }
}

// ------------------------------------------------------------------ launch
extern "C" void kernel_launch(void* const* d_in, const int* in_sizes, int n_in,
                              void* d_out, int out_size, void* d_ws, size_t ws_size,
                              hipStream_t stream) {
    const float* x0  = (const float*)d_in[0];
    const float* spa = (const float*)d_in[1];
    const float* gum = (const float*)d_in[2];
    const float* chm = (const float*)d_in[3];
    const float* w0  = (const float*)d_in[4];
    const float* w1  = (const float*)d_in[5];
    const float* w2  = (const float*)d_in[6];
    const float* w3  = (const float*)d_in[7];
    const float* wc  = (const float*)d_in[8];
    const float* bias= (const float*)d_in[9];
    float* out = (float*)d_out;

    char* ws = (char*)d_ws;
    const size_t WBASE = (1u<<20);
    const size_t FB = 67699712ull;                 // padded fea buffer + 64KB tail
    const size_t NEED_A = WBASE + 3*FB;            // fused path: fea4 never materialized
    const size_t NEED_B = WBASE + 2*FB;
    if (ws_size < NEED_B) return;

    float* ws_ch = (float*)ws;
    f16* bpk0 = (f16*)(ws + 4096);
    f16* bpkL = (f16*)(ws + 4096 + 73728);
    f16* wcpk = (f16*)(ws + 4096 + 73728 + 442368);

    dim3 gcv(2048, 1, 1);   // conv: flat grid, XCD-swizzled decode in-kernel
    dim3 gcf(8, 512, 2);    // fallback collect: 64-px tiles
    const int SETUP_GRID = (36864 + 221184 + 16384 + 512 + 3*32832 + 255) / 256;

    if (ws_size >= NEED_A) {
        f16* R1 = (f16*)(ws + WBASE);
        f16* R2 = (f16*)(ws + WBASE + FB);
        f16* R3 = (f16*)(ws + WBASE + 2*FB);
        k_setup<<<SETUP_GRID, 256, 0, stream>>>(w0, w1, w2, w3, wc, gum, chm,
                ws_ch, out + 33554432, bpk0, bpkL, wcpk, R1, R2, R3);
        k_conv<0><<<gcv, 256, 0, stream>>>(x0, R1, bpk0,          ws_ch + 0,   spa,
                nullptr, nullptr, nullptr, nullptr, nullptr);
        k_conv<1><<<gcv, 256, 0, stream>>>(R1, R2, bpkL + 0,      ws_ch + 128, spa,
                nullptr, nullptr, nullptr, nullptr, nullptr);
        k_conv<1><<<gcv, 256, 0, stream>>>(R2, R3, bpkL + 73728,  ws_ch + 256, spa,
                nullptr, nullptr, nullptr, nullptr, nullptr);
        k_conv<2><<<gcv, 256, 0, stream>>>(R3, nullptr, bpkL + 147456, ws_ch + 384, spa,
                R1, R2, wcpk, bias, out);
    } else {
        f16* P0 = (f16*)(ws + WBASE);
        f16* P1 = (f16*)(ws + WBASE + FB);
        k_setup<<<SETUP_GRID, 256, 0, stream>>>(w0, w1, w2, w3, wc, gum, chm,
                ws_ch, out + 33554432, bpk0, bpkL, wcpk, P0, P1, P0);
        k_conv<0><<<gcv, 256, 0, stream>>>(x0, P1, bpk0,          ws_ch + 0,   spa,
                nullptr, nullptr, nullptr, nullptr, nullptr);
        k_collect<true ><<<gcf, 256, 0, stream>>>(P1, wcpk + 0,     bias, out);
        k_conv<1><<<gcv, 256, 0, stream>>>(P1, P0, bpkL + 0,      ws_ch + 128, spa,
                nullptr, nullptr, nullptr, nullptr, nullptr);
        k_collect<false><<<gcf, 256, 0, stream>>>(P0, wcpk + 4096,  bias, out);
        k_conv<1><<<gcv, 256, 0, stream>>>(P0, P1, bpkL + 73728,  ws_ch + 256, spa,
                nullptr, nullptr, nullptr, nullptr, nullptr);
        k_collect<false><<<gcf, 256, 0, stream>>>(P1, wcpk + 8192,  bias, out);
        k_conv<1><<<gcv, 256, 0, stream>>>(P1, P0, bpkL + 147456, ws_ch + 384, spa,
                nullptr, nullptr, nullptr, nullptr, nullptr);
        k_collect<false><<<gcf, 256, 0, stream>>>(P0, wcpk + 12288, bias, out);
    }
}

// Round 21
// 318.809 us; speedup vs baseline: 1.1032x; 1.0050x over previous
//
#include <hip/hip_runtime.h>
#include <hip/hip_fp16.h>

#define BB 2
#define HH 512
#define WW 512
#define CC 64
#define PW 514

typedef _Float16 f16;
typedef _Float16 f16x8 __attribute__((ext_vector_type(8)));
typedef _Float16 f16x4 __attribute__((ext_vector_type(4)));
typedef float f32x4 __attribute__((ext_vector_type(4)));

static __device__ __forceinline__ f16x8 zero_f16x8() {
    f16x8 z = {(f16)0,(f16)0,(f16)0,(f16)0,(f16)0,(f16)0,(f16)0,(f16)0};
    return z;
}

static __device__ __forceinline__ f16x8 cvt_pair(f32x4 a, f32x4 b) {
    f16x8 o;
    o[0]=(f16)a[0]; o[1]=(f16)a[1]; o[2]=(f16)a[2]; o[3]=(f16)a[3];
    o[4]=(f16)b[0]; o[5]=(f16)b[1]; o[6]=(f16)b[2]; o[7]=(f16)b[3];
    return o;
}

// softmax weight for (l, side, c) of the gumbel channel mask
static __device__ __forceinline__ float ch_scale(const float* gum, const float* chm,
                                                 int l, int side, int c) {
    float u0 = gum[(l*2+0)*64+c], u1 = gum[(l*2+1)*64+c];
    u0 = fminf(fmaxf(u0, 1e-10f), 1.0f);
    u1 = fminf(fmaxf(u1, 1e-10f), 1.0f);
    float a0 = chm[(l*2+0)*64+c] - logf(-logf(u0));
    float a1 = chm[(l*2+1)*64+c] - logf(-logf(u1));
    float m = fmaxf(a0, a1);
    float e0 = expf(a0-m), e1 = expf(a1-m);
    float s = e0 + e1;
    return (side == 0) ? e0/s : e1/s;
}

// ------------------------------------------------- fused setup (one launch)
__global__ void k_setup(const float* __restrict__ w0, const float* __restrict__ w1,
                        const float* __restrict__ w2, const float* __restrict__ w3,
                        const float* __restrict__ wc, const float* __restrict__ gum,
                        const float* __restrict__ chm,
                        float* __restrict__ ws_ch, float* __restrict__ out_ch,
                        f16* __restrict__ bpk0, f16* __restrict__ bpkL,
                        f16* __restrict__ wcpk,
                        f16* __restrict__ g1, f16* __restrict__ g2, f16* __restrict__ g3) {
    int idx = blockIdx.x * 256 + threadIdx.x;
    if (idx < 36864) {
        int j = idx & 7, lane = (idx>>3)&63, nb = (idx>>9)&3, kb = idx>>11;
        int k = kb*32 + (lane>>4)*8 + j;
        int tap = k>>6, ci = k&63;
        int co = nb*16 + (lane&15);
        bpk0[idx] = (f16)w0[(tap*64+ci)*64+co];
    } else if (idx < 36864 + 221184) {
        int i2 = idx - 36864;
        int l = i2 / 73728;               // 0..2 -> layer l+1, masks from ch[l]
        int r = i2 % 73728;
        int j = r&7, lane=(r>>3)&63, nb=(r>>9)&7, kb=r>>12;
        int k = kb*32 + (lane>>4)*8 + j;
        int tap = k>>6, ci = k&63;
        int copr = nb*16 + (lane&15);     // [0:64)=dense, [64:128)=sparse
        int co = copr & 63;
        const float* w = (l==0)? w1 : (l==1)? w2 : w3;
        float scale = ch_scale(gum, chm, l, (copr < 64) ? 0 : 1, ci);
        bpkL[i2] = (f16)(w[(tap*64+ci)*64+co] * scale);
    } else if (idx < 36864 + 221184 + 16384) {
        int i3 = idx - (36864 + 221184);
        int j=i3&7, lane=(i3>>3)&63, nb=(i3>>9)&3, kb=(i3>>11)&1, l=i3>>12;
        int k = kb*32 + (lane>>4)*8 + j;
        int n = nb*16 + (lane&15);
        wcpk[i3] = (f16)wc[(l*64+k)*64+n];
    } else if (idx < 36864 + 221184 + 16384 + 512) {
        int t = idx - (36864 + 221184 + 16384);
        int l = t >> 7, sc = t & 127;
        int side = sc >> 6, c = sc & 63;
        float v = ch_scale(gum, chm, l, side, c);
        ws_ch[(l*2+side)*64+c] = v;
        out_ch[(l*2+side)*64+c] = v;
    } else {
        int g = idx - (36864 + 221184 + 16384 + 512);
        const int TOT = 2*2052*8;
        if (g >= 3*TOT) return;
        f16* buf = (g < TOT) ? g1 : (g < 2*TOT) ? g2 : g3;
        int e = g % TOT;
        int c8 = e & 7, gg = e >> 3;
        int b = gg / 2052, r = gg % 2052;
        int hp, wp;
        if      (r < 514)  { hp = 0;        wp = r; }
        else if (r < 1028) { hp = 513;      wp = r-514; }
        else if (r < 1540) { hp = r-1027;   wp = 0; }
        else               { hp = r-1539;   wp = 513; }
        *(f16x8*)(buf + ((size_t)(b*PW+hp)*PW + wp)*64 + c8*8) = zero_f16x8();
    }
}

// ------------------------------------------------------------------- conv
// Block: 4 waves = 2 rows (wr) x 2 col-halves (wn); tile 128 px x 2 rows.
// XCD-AWARE SWIZZLE (T1): flat grid 2048; xcd = bid&7 = (b, wt) strip.
// MODE 0: raw f32 x0 -> fea1 (fused cvt staging).
// MODE 1: padded f16 -> padded f16 (global_load_lds staging, 2 phases).
// MODE 2: layer-3 conv FUSED with collect. Conv P tile kept in LDS:
//   P row 0 -> slot-0 region [0,16384), P row 1 -> slot-3 region
//   [52224, 52224+16384) (both dead after the conv loop); slots 1,2 keep
//   the STAGED fea3 rows h0+1,h0+2 so phase 2 reads fea3 from LDS too.
//   Phase 2: out[p,:] = sum_l fea_l[p,:] @ Wc_l + bias, fea1/2 from global,
//   fea3 + fea4(P) from LDS. fea4 never hits HBM.
// A/B reg-double-buffered; MFMAs under setprio(1); LDS XOR-swizzle (rule 21).
template<int MODE>
__global__ __launch_bounds__(256, 2) void k_conv(const void* __restrict__ in_, f16* __restrict__ out,
        const f16* __restrict__ bpk, const float* __restrict__ ch_l,
        const float* __restrict__ spa,
        const f16* __restrict__ fA, const f16* __restrict__ fB,
        const f16* __restrict__ wcpk, const float* __restrict__ bias,
        float* __restrict__ outF) {
    constexpr int NBT = (MODE==0) ? 4 : 8;
    constexpr int NF  = (MODE==0) ? 2 : 4;
    __shared__ f16 smem[4*136*64];                 // 69632 B
    const int bid = blockIdx.x;
    const int xcd = bid & 7;
    const int wt  = xcd & 3;
    const int b   = xcd >> 2;
    const int hb  = bid >> 3;                      // 0..255, contiguous per XCD
    const int h0 = hb*2;
    const int tid = threadIdx.x, lane = tid & 63, wid = tid >> 6;
    const int px0 = wt*128;
    const int sub  = lane & 7;
    const int srel = lane >> 3;
    const int cblk = sub ^ srel;                   // s&7 == srel for s=i*8+srel

    if (MODE == 0) {
        const float* inF = (const float*)in_;
        #pragma unroll
        for (int half = 0; half < 2; ++half) {
            const int J0 = half ? 9 : 0;
            const int JN = half ? 8 : 9;
            f32x4 v0[9], v1[9];
            bool ok[9];
            int dst[9];
            #pragma unroll
            for (int t = 0; t < JN; ++t) {
                int j = (J0 + t)*4 + wid;          // 0..67
                int r = j / 17, i = j % 17;
                int s = i*8 + srel;
                int hin = h0 + r - 1;
                int win = px0 + s - 1;
                ok[t] = ((unsigned)hin < HH) && ((unsigned)win < WW);
                dst[t] = r*17408 + i*1024 + lane*16;
                if (ok[t]) {
                    const f32x4* p = (const f32x4*)(inF + (((size_t)(b*HH + hin)*WW + win)*CC + cblk*8));
                    v0[t] = p[0];
                    v1[t] = p[1];
                }
            }
            #pragma unroll
            for (int t = 0; t < JN; ++t) {
                f16x8 o = ok[t] ? cvt_pair(v0[t], v1[t]) : zero_f16x8();
                if ((J0 + t)*4 + wid < 68)
                    *(f16x8*)((char*)smem + dst[t]) = o;
            }
        }
        __syncthreads();
    } else {
        const f16* inH = (const f16*)in_;
        #pragma unroll
        for (int jj = 0; jj < 9; ++jj) {
            int j = jj*4 + wid;
            if (j < 34) {
                int r = j / 17, i = j % 17;
                int s = i*8 + srel;
                const f16* src = inH + ((size_t)(b*PW + h0 + r)*PW + (px0 + s))*64 + cblk*8;
                __builtin_amdgcn_global_load_lds(
                    (const __attribute__((address_space(1))) uint32_t*)src,
                    (__attribute__((address_space(3))) uint32_t*)
                        ((char*)smem + r*17408 + i*1024),
                    16, 0, 0);
            }
        }
        __syncthreads();
        #pragma unroll
        for (int jj = 0; jj < 9; ++jj) {
            int j = 34 + jj*4 + wid;
            if (j < 68) {
                int r = j / 17, i = j % 17;
                int s = i*8 + srel;
                const f16* src = inH + ((size_t)(b*PW + h0 + r)*PW + (px0 + s))*64 + cblk*8;
                __builtin_amdgcn_global_load_lds(
                    (const __attribute__((address_space(1))) uint32_t*)src,
                    (__attribute__((address_space(3))) uint32_t*)
                        ((char*)smem + r*17408 + i*1024),
                    16, 0, 0);
            }
        }
    }

    const int wr = wid >> 1, wn = wid & 1;
    const int lrow = lane & 15, q = lane >> 4;
    const char* smw = (const char*)smem + wr*17408;   // wave's row-0 base

    int sb[8][3], po[2][3];
    #pragma unroll
    for (int dxi = 0; dxi < 3; ++dxi) {
        int m7 = (lrow + dxi) & 7;
        po[0][dxi] = ((q)     ^ m7) * 16;
        po[1][dxi] = ((4 + q) ^ m7) * 16;
        #pragma unroll
        for (int mf = 0; mf < 8; ++mf)
            sb[mf][dxi] = (mf*16 + lrow + dxi) * 128;
    }

    f32x4 acc[8][NF];
    #pragma unroll
    for (int i=0;i<8;i++)
        #pragma unroll
        for (int j=0;j<NF;j++) { f32x4 z = {0.f,0.f,0.f,0.f}; acc[i][j] = z; }

    int nbIdx[4];
    nbIdx[0]=wn*2; nbIdx[1]=wn*2+1; nbIdx[2]=wn*2+4; nbIdx[3]=wn*2+5;

    const f16* blane = bpk + (size_t)lane*8;       // + kb*NBT*512 + nb*512

    f16x8 acur[8], anxt[8], bcur[NF], bnxt[NF];
    #pragma unroll
    for (int nf=0; nf<NF; ++nf)
        bcur[nf] = *reinterpret_cast<const f16x8*>(blane + (size_t)nbIdx[nf]*512);
    #pragma unroll
    for (int mf=0; mf<8; ++mf)
        acur[mf] = *(const f16x8*)(smw + sb[mf][0] + po[0][0]);

    #pragma unroll
    for (int kb = 0; kb < 18; ++kb) {
        if (MODE >= 1 && kb == 5) __syncthreads(); // rows 2,3 ready; drained under kb0-4
        if (kb < 17) {
            const int kn = kb + 1;
            const int rn = kn/6, dxin = (kn%6)/2, halfn = kn & 1;
            #pragma unroll
            for (int nf=0; nf<NF; ++nf)
                bnxt[nf] = *reinterpret_cast<const f16x8*>(blane + (size_t)(kn*NBT + nbIdx[nf])*512);
            #pragma unroll
            for (int mf=0; mf<8; ++mf)
                anxt[mf] = *(const f16x8*)(smw + rn*17408 + sb[mf][dxin] + po[halfn][dxin]);
        }
        __builtin_amdgcn_s_setprio(1);
        #pragma unroll
        for (int nf=0; nf<NF; ++nf) {
            #pragma unroll
            for (int mf=0; mf<8; ++mf) {
                if (MODE == 2)
                    acc[mf][nf] = __builtin_amdgcn_mfma_f32_16x16x32_f16(bcur[nf], acur[mf], acc[mf][nf], 0,0,0);
                else
                    acc[mf][nf] = __builtin_amdgcn_mfma_f32_16x16x32_f16(acur[mf], bcur[nf], acc[mf][nf], 0,0,0);
            }
        }
        __builtin_amdgcn_s_setprio(0);
        #pragma unroll
        for (int nf=0; nf<NF; ++nf) bcur[nf] = bnxt[nf];
        #pragma unroll
        for (int mf=0; mf<8; ++mf) acur[mf] = anxt[mf];
    }

    const float* cd = ch_l;
    const float* cs = ch_l + 64;
    const int h = h0 + wr;
    const size_t sparow = (size_t)(b*HH + h)*WW;

    if (MODE != 2) {
        const size_t outrow = (size_t)(b*PW + h + 1)*PW + 1;
        #pragma unroll
        for (int mf=0; mf<8; ++mf) {
            const int pixb = mf*16 + q*4;
            f32x4 sp4 = *(const f32x4*)(spa + sparow + px0 + pixb);
            float sp[4] = {sp4[0], sp4[1], sp4[2], sp4[3]};
            #pragma unroll
            for (int nf2=0; nf2<2; ++nf2) {
                int co = wn*32 + nf2*16 + lrow;
                float vcd = cd[co], vcs = cs[co];
                #pragma unroll
                for (int r=0; r<4; ++r) {
                    float v;
                    if (MODE==0) v = acc[mf][nf2][r] * (vcs*sp[r] + vcd);
                    else         v = acc[mf][nf2][r] * (vcs*sp[r] + vcd) + acc[mf][nf2+2][r] * sp[r];
                    v = fmaxf(v, 0.f);
                    out[(outrow + px0 + pixb + r)*64 + co] = (f16)v;
                }
            }
        }
        return;
    }

    // ---------------- MODE 2: epilogue -> LDS P tile, then fused collect ----
    __syncthreads();                               // staged A fully consumed
    {
        // Transposed C: per (mf,nf2) lane holds co = wn*32+nf2*16+q*4..+3 at
        // pixel = mf*16 + lrow. P row wr -> slot-0 / slot-3 region (16 KB
        // each); slots 1,2 keep staged fea3 for phase 2.
        const int pbase = wr ? 52224 : 0;
        #pragma unroll
        for (int mf=0; mf<8; ++mf) {
            const int pix = mf*16 + lrow;
            const float sp = spa[sparow + px0 + pix];
            #pragma unroll
            for (int nf2=0; nf2<2; ++nf2) {
                const int co0 = wn*32 + nf2*16 + q*4;
                f32x4 cd4 = *(const f32x4*)(cd + co0);
                f32x4 cs4 = *(const f32x4*)(cs + co0);
                f16x4 o;
                #pragma unroll
                for (int r=0; r<4; ++r) {
                    float v = acc[mf][nf2][r] * (cs4[r]*sp + cd4[r]) + acc[mf][nf2+2][r] * sp;
                    o[r] = (f16)fmaxf(v, 0.f);
                }
                const int chunk = co0 >> 3;        // wn*4 + nf2*2 + (q>>1)
                const int addr = pbase + pix*128 + ((chunk ^ (pix & 7))*16) + (q & 1)*8;
                *(f16x4*)((char*)smem + addr) = o;
            }
        }
    }
    __syncthreads();                               // P tile complete

    {
        const int row2 = wid >> 1;                 // waves 0,1 -> row 0; 2,3 -> row 1
        const int pxc  = (wid & 1)*64;             // wave's 64-px half
        const int h2 = h0 + row2;
        const size_t inrow2  = (size_t)(b*PW + h2 + 1)*PW + 1;
        const size_t outrow2 = (size_t)(b*HH + h2)*WW;
        const int lk = q*8;
        const int pbase2 = row2 ? 52224 : 0;

        f32x4 acc2[4][4];
        #pragma unroll
        for (int i=0;i<4;i++)
            #pragma unroll
            for (int j=0;j<4;j++) { f32x4 z = {0.f,0.f,0.f,0.f}; acc2[i][j] = z; }

        #pragma unroll
        for (int kb=0; kb<8; ++kb) {
            f16x8 a[4];
            if (kb < 4) {
                const f16* fl = (kb < 2) ? fA : fB;
                #pragma unroll
                for (int mf2=0; mf2<4; ++mf2)
                    a[mf2] = *reinterpret_cast<const f16x8*>(fl + (inrow2 + px0 + pxc + mf2*16 + lrow)*64 + (kb&1)*32 + lk);
            } else if (kb < 6) {
                // fea3 from the STAGED input: padded row h0+row2+1 = slot row2+1
                const int cc = (kb&1)*4 + q;
                #pragma unroll
                for (int mf2=0; mf2<4; ++mf2) {
                    const int s2 = pxc + mf2*16 + lrow + 1;
                    a[mf2] = *(const f16x8*)((const char*)smem + (row2+1)*17408 + s2*128 + ((cc ^ (s2 & 7))*16));
                }
            } else {
                const int chunk = (kb-6)*4 + q;
                #pragma unroll
                for (int mf2=0; mf2<4; ++mf2) {
                    const int pixl = pxc + mf2*16 + lrow;
                    a[mf2] = *(const f16x8*)((const char*)smem + pbase2 + pixl*128 + ((chunk ^ (pixl & 7))*16));
                }
            }
            #pragma unroll
            for (int nf=0; nf<4; ++nf) {
                f16x8 bb = *reinterpret_cast<const f16x8*>(wcpk + ((size_t)(kb*4 + nf)*64 + lane)*8);
                #pragma unroll
                for (int mf2=0; mf2<4; ++mf2)
                    acc2[mf2][nf] = __builtin_amdgcn_mfma_f32_16x16x32_f16(bb, a[mf2], acc2[mf2][nf], 0,0,0);
            }
        }
        #pragma unroll
        for (int mf2=0; mf2<4; ++mf2) {
            const int pixg = px0 + pxc + mf2*16 + lrow;
            float* orow = outF + (outrow2 + pixg)*CC;
            #pragma unroll
            for (int nf=0; nf<4; ++nf) {
                const int co0 = nf*16 + q*4;
                f32x4 b4 = *(const f32x4*)(bias + co0);
                *(f32x4*)(orow + co0) = acc2[mf2][nf] + b4;
            }
        }
    }
}

// --------------------------------------- collect fallback (per-layer RMW)
template<bool FIRST>
__global__ __launch_bounds__(256) void k_collect(const f16* __restrict__ fea,
        const f16* __restrict__ wcpk_l, const float* __restrict__ bias,
        float* __restrict__ out) {
    const int wt = blockIdx.x, h = blockIdx.y, b = blockIdx.z;
    const int tid = threadIdx.x;
    const int lane = tid & 63, wid = tid >> 6;
    const int lrow = lane & 15, lk = (lane>>4)*8;
    const size_t inrow  = (size_t)(b*PW + h + 1)*PW + 1;
    const size_t outrow = (size_t)(b*HH + h)*WW;
    const int px0 = wt*64 + wid*16;

    f32x4 acc[4];
    #pragma unroll
    for (int j=0;j<4;j++) { f32x4 z = {0.f,0.f,0.f,0.f}; acc[j] = z; }

    #pragma unroll
    for (int kb=0; kb<2; ++kb) {
        f16x8 a = *reinterpret_cast<const f16x8*>(fea + (inrow + px0 + lrow)*64 + kb*32 + lk);
        #pragma unroll
        for (int nf=0; nf<4; ++nf) {
            f16x8 bb = *reinterpret_cast<const f16x8*>(wcpk_l + ((size_t)(kb*4 + nf)*64 + lane)*8);
            acc[nf] = __builtin_amdgcn_mfma_f32_16x16x32_f16(bb, a, acc[nf], 0,0,0);
        }
    }
    const int q = lane >> 4;
    const int pix = px0 + lrow;
    float* orow = out + (outrow + pix)*CC;
    #pragma unroll
    for (int nf=0; nf<4; ++nf) {
        const int co0 = nf*16 + q*4;
        f32x4 v = acc[nf];
        #pragma unroll
        for (int r=0;r<4;++r) {
            float x = v[r];
            if (FIRST) x += bias[co0+r];
            else       x += orow[co0+r];
            orow[co0+r] = x;
        }
    }
}

// ------------------------------------------------------------------ launch
extern "C" void kernel_launch(void* const* d_in, const int* in_sizes, int n_in,
                              void* d_out, int out_size, void* d_ws, size_t ws_size,
                              hipStream_t stream) {
    const float* x0  = (const float*)d_in[0];
    const float* spa = (const float*)d_in[1];
    const float* gum = (const float*)d_in[2];
    const float* chm = (const float*)d_in[3];
    const float* w0  = (const float*)d_in[4];
    const float* w1  = (const float*)d_in[5];
    const float* w2  = (const float*)d_in[6];
    const float* w3  = (const float*)d_in[7];
    const float* wc  = (const float*)d_in[8];
    const float* bias= (const float*)d_in[9];
    float* out = (float*)d_out;

    char* ws = (char*)d_ws;
    const size_t WBASE = (1u<<20);
    const size_t FB = 67699712ull;                 // padded fea buffer + 64KB tail
    const size_t NEED_A = WBASE + 3*FB;            // fused path: fea4 never materialized
    const size_t NEED_B = WBASE + 2*FB;
    if (ws_size < NEED_B) return;

    float* ws_ch = (float*)ws;
    f16* bpk0 = (f16*)(ws + 4096);
    f16* bpkL = (f16*)(ws + 4096 + 73728);
    f16* wcpk = (f16*)(ws + 4096 + 73728 + 442368);

    dim3 gcv(2048, 1, 1);   // conv: flat grid, XCD-swizzled decode in-kernel
    dim3 gcf(8, 512, 2);    // fallback collect: 64-px tiles
    const int SETUP_GRID = (36864 + 221184 + 16384 + 512 + 3*32832 + 255) / 256;

    if (ws_size >= NEED_A) {
        f16* R1 = (f16*)(ws + WBASE);
        f16* R2 = (f16*)(ws + WBASE + FB);
        f16* R3 = (f16*)(ws + WBASE + 2*FB);
        k_setup<<<SETUP_GRID, 256, 0, stream>>>(w0, w1, w2, w3, wc, gum, chm,
                ws_ch, out + 33554432, bpk0, bpkL, wcpk, R1, R2, R3);
        k_conv<0><<<gcv, 256, 0, stream>>>(x0, R1, bpk0,          ws_ch + 0,   spa,
                nullptr, nullptr, nullptr, nullptr, nullptr);
        k_conv<1><<<gcv, 256, 0, stream>>>(R1, R2, bpkL + 0,      ws_ch + 128, spa,
                nullptr, nullptr, nullptr, nullptr, nullptr);
        k_conv<1><<<gcv, 256, 0, stream>>>(R2, R3, bpkL + 73728,  ws_ch + 256, spa,
                nullptr, nullptr, nullptr, nullptr, nullptr);
        k_conv<2><<<gcv, 256, 0, stream>>>(R3, nullptr, bpkL + 147456, ws_ch + 384, spa,
                R1, R2, wcpk, bias, out);
    } else {
        f16* P0 = (f16*)(ws + WBASE);
        f16* P1 = (f16*)(ws + WBASE + FB);
        k_setup<<<SETUP_GRID, 256, 0, stream>>>(w0, w1, w2, w3, wc, gum, chm,
                ws_ch, out + 33554432, bpk0, bpkL, wcpk, P0, P1, P0);
        k_conv<0><<<gcv, 256, 0, stream>>>(x0, P1, bpk0,          ws_ch + 0,   spa,
                nullptr, nullptr, nullptr, nullptr, nullptr);
        k_collect<true ><<<gcf, 256, 0, stream>>>(P1, wcpk + 0,     bias, out);
        k_conv<1><<<gcv, 256, 0, stream>>>(P1, P0, bpkL + 0,      ws_ch + 128, spa,
                nullptr, nullptr, nullptr, nullptr, nullptr);
        k_collect<false><<<gcf, 256, 0, stream>>>(P0, wcpk + 4096,  bias, out);
        k_conv<1><<<gcv, 256, 0, stream>>>(P0, P1, bpkL + 73728,  ws_ch + 256, spa,
                nullptr, nullptr, nullptr, nullptr, nullptr);
        k_collect<false><<<gcf, 256, 0, stream>>>(P1, wcpk + 8192,  bias, out);
        k_conv<1><<<gcv, 256, 0, stream>>>(P1, P0, bpkL + 147456, ws_ch + 384, spa,
                nullptr, nullptr, nullptr, nullptr, nullptr);
        k_collect<false><<<gcf, 256, 0, stream>>>(P0, wcpk + 12288, bias, out);
    }
}